// Round 17
// baseline (138.356 us; speedup 1.0000x reference)
//
#include <hip/hip_runtime.h>

typedef unsigned short u16;
typedef unsigned int u32;
typedef __bf16 bf16x8 __attribute__((ext_vector_type(8)));
typedef float f32x4 __attribute__((ext_vector_type(4)));
typedef u32 u32x4 __attribute__((ext_vector_type(4)));

// kTr[((t*2+nh)*2+nt)*2+kb][lane][j] : per-lane-ordered repack -> every
// B-load is one fully-contiguous 1KB wave read (8 fully-used cachelines).
__device__ __align__(16) u16 g_kTr[27 * 8 * 512];

__device__ __forceinline__ u32 pack_bf(float a, float b) {
    u32 ua = __float_as_uint(a) + 0x8000u;   // round-half-up
    u32 ub = __float_as_uint(b) + 0x8000u;
    return __builtin_amdgcn_perm(ub, ua, 0x07060302u);
}

// ---------------------------------------------------------------------------
// build_k: kTr (+ fold self-connection into center tap). 27 blocks x 64.
// ---------------------------------------------------------------------------
__global__ __launch_bounds__(64) void build_k(
    const float* __restrict__ Wsc0, const float* __restrict__ Wsc1,
    const float* __restrict__ w1, const float* __restrict__ w2,
    const float* __restrict__ w3, const float* __restrict__ w4)
{
    const int t = blockIdx.x;
    const int c = threadIdx.x;
    const int dx = t / 9 - 1, dy = (t / 3) % 3 - 1, dz = t % 3 - 1;
    const float d = sqrtf((float)(dx * dx + dy * dy + dz * dz));
    const float step = 1.5f / 9.0f;
    float emb[8];
#pragma unroll
    for (int k = 0; k < 8; ++k) {
        float diff = (d - (float)(k + 1) * step) / step;
        float q = diff * diff;
        emb[k] = (q < 1.0f) ? 1.14136f * expf(2.0f - 2.0f / (1.0f - q)) : 0.0f;
    }
    const float dn = fmaxf(d, 1e-12f);
    const float s3 = 1.7320508075688772f;
    const float sh1[3] = { s3 * dx / dn, s3 * dy / dn, s3 * dz / dn };
    const float alpha  = 0.17677669529663687f;
    const float alpha3 = alpha * 0.57735026918962576f;

    const int base2 = ((t * 2 + (c >> 5)) * 2 + ((c >> 4) & 1)) * 2;
    const int l15c  = c & 15;
    auto put = [&](int r, float v) {
        u32 u = __float_as_uint(v);
        u += 0x7FFFu + ((u >> 16) & 1u);
        g_kTr[(base2 + (r >> 5)) * 512 + (((r >> 3) & 3) * 16 + l15c) * 8 + (r & 7)] =
            (u16)(u >> 16);
    };

    if (c < 16) {
        const int o = c;
#pragma unroll
        for (int i = 0; i < 16; ++i) {
            float W1 = 0.f, W4 = 0.f;
#pragma unroll
            for (int k = 0; k < 8; ++k) {
                W1 += emb[k] * w1[k * 256 + i * 16 + o];
                W4 += emb[k] * w4[k * 256 + i * 16 + o];
            }
            W1 *= (1.0f / 27.0f); W4 *= (1.0f / 27.0f);
            float v0 = alpha * W1;
            if (t == 13) v0 += 0.25f * Wsc0[i * 16 + o];
            put(i, v0);
            const float base = alpha3 * W4;
#pragma unroll
            for (int m = 0; m < 3; ++m) put(16 + 3 * i + m, base * sh1[m]);
        }
    } else {
        const int o = (c - 16) / 3, nc = (c - 16) % 3;
#pragma unroll
        for (int i = 0; i < 16; ++i) {
            float W2 = 0.f, W3 = 0.f;
#pragma unroll
            for (int k = 0; k < 8; ++k) {
                W2 += emb[k] * w2[k * 256 + i * 16 + o];
                W3 += emb[k] * w3[k * 256 + i * 16 + o];
            }
            W2 *= (1.0f / 27.0f); W3 *= (1.0f / 27.0f);
            put(i, alpha * W2 * sh1[nc]);
#pragma unroll
            for (int m = 0; m < 3; ++m) {
                float v = (m == nc) ? alpha * W3 : 0.0f;
                if (t == 13 && m == nc) v += 0.25f * Wsc1[i * 16 + o];
                put(16 + 3 * i + m, v);
            }
        }
    }
}

// ---------------------------------------------------------------------------
// v12 = v11 with 8 waves / 512 threads -> 2 waves/SIMD (TLP for stall fill).
// Wave (yh 0..3, nh 0..1): M = 1y x 32z = 32, N = 32 ch. Same dbuf, same
// fused staging (1 SLD + 1 SWR per tap region, 10 chunks/wave, 3 F slots).
// ---------------------------------------------------------------------------
#define BUFU16 39424   // 77 * 512 u16 per buffer

#define WALL() __builtin_amdgcn_sched_barrier(0);

#define LOADB(S, T) { \
  const u32x4* _p = reinterpret_cast<const u32x4*>(bTr + (T) * 8192); \
  B##S##0 = _p[0]; B##S##1 = _p[64]; B##S##2 = _p[128]; B##S##3 = _p[192]; }

#define LOADA2(s, i0, i1, RCC) { \
  const int _r  = rbase + (RCC); \
  const int _o0 = _r * 128 + ((kg ^ (_r & 7)) << 4); \
  A##s##_##i0 = *reinterpret_cast<const bf16x8*>(abase + _o0); \
  A##s##_##i1 = *reinterpret_cast<const bf16x8*>(abase + (_o0 ^ 64)); }

// row = (dx*6 + dy + yh)*34 + dz + mt*16 ; rbase = yh*34 + l15
#define RCCW(T, MT) ((((T)/9)*6 + (((T)/3)%3))*34 + ((T)%3) + (MT)*16)

#define LOAD_A4(s, T) \
  LOADA2(s, 0, 1, RCCW(T,0)) \
  LOADA2(s, 2, 3, RCCW(T,1))

// stage-load chunk (wv*10 + C) of tile (bs,Xs,ys0) into fp32 slot S
#define SLD(S, C) { \
  const int _c   = wv * 10 + (C); \
  const int _row = _c * 8 + rloc; \
  const int _rid = _row / 204; \
  const int _rem = _row - _rid * 204; \
  const int _yi  = _rem / 34; \
  const int _zid = _rem - _yi * 34; \
  const int _xin = Xs + _rid - 1; \
  const int _yin = ys0 + _yi - 1; \
  const int _zin = _zid - 1; \
  const bool _ib = (_row < 612) && ((unsigned)_xin < 32u) && \
                   ((unsigned)_yin < 32u) && ((unsigned)_zin < 32u); \
  F##S##a = (f32x4){0.f, 0.f, 0.f, 0.f}; \
  F##S##b = (f32x4){0.f, 0.f, 0.f, 0.f}; \
  if (_ib) { \
    const f32x4* _p = reinterpret_cast<const f32x4*>( \
        x + ((size_t)(((bs * 32 + _xin) * 32 + _yin) * 32 + _zin) * 64 + swz * 8)); \
    F##S##a = _p[0]; F##S##b = _p[1]; \
  } }

#define SWR(S, C) { \
  const int _c = wv * 10 + (C); \
  if (_c < 77) { \
    u32x4 _pk; \
    _pk[0] = pack_bf(F##S##a[0], F##S##a[1]); \
    _pk[1] = pack_bf(F##S##a[2], F##S##a[3]); \
    _pk[2] = pack_bf(F##S##b[0], F##S##b[1]); \
    _pk[3] = pack_bf(F##S##b[2], F##S##b[3]); \
    *reinterpret_cast<u32x4*>(bufn + _c * 512 + lane * 8) = _pk; \
  } }

#define BC(x) __builtin_bit_cast(bf16x8, x)
#define MF(b_, a_, c_) __builtin_amdgcn_mfma_f32_16x16x32_bf16(BC(b_), a_, c_, 0, 0, 0)

// acc{mt}{nt}; B: s0=nt0kb0 s1=nt0kb1 s2=nt1kb0 s3=nt1kb1; A idx = mt*2+kb
#define MFMA8(bs, as) \
  acc00 = MF(B##bs##0, A##as##_0, acc00); acc01 = MF(B##bs##2, A##as##_0, acc01); \
  acc10 = MF(B##bs##0, A##as##_2, acc10); acc11 = MF(B##bs##2, A##as##_2, acc11); \
  acc00 = MF(B##bs##1, A##as##_1, acc00); acc01 = MF(B##bs##3, A##as##_1, acc01); \
  acc10 = MF(B##bs##1, A##as##_3, acc10); acc11 = MF(B##bs##3, A##as##_3, acc11);

__global__ __launch_bounds__(512, 1) void conv_mfma12(
    const float* __restrict__ x, float* __restrict__ out)
{
    extern __shared__ u16 xt[];   // 2 * 78848 B

    const int blk   = blockIdx.x;
    const int tbase = ((blk & 7) * 32 + (blk >> 3)) * 4;   // XCD-contiguous
    const int tid   = threadIdx.x;
    const int wv    = tid >> 6;      // 0..7
    const int lane  = tid & 63;
    const int l15   = lane & 15;
    const int kg    = lane >> 4;
    const int yh    = wv >> 1;       // 0..3 (one y-row each)
    const int nh    = wv & 1;
    const int rloc  = lane >> 3;
    const int swz   = (lane & 7) ^ rloc;
    const int rbase = yh * 34 + l15;

    const char* bTr = (const char*)g_kTr + nh * 4096 + lane * 16;

    u32x4 B00, B01, B02, B03, B10, B11, B12, B13, B20, B21, B22, B23;
    bf16x8 A0_0, A0_1, A0_2, A0_3;
    bf16x8 A1_0, A1_1, A1_2, A1_3;
    f32x4 F0a, F0b, F1a, F1b, F2a, F2b;

    // ---- prologue: stage tile 0 into buffer 0 (compiler-scheduled) ----
    {
        const int ts = tbase;
        const int bs = ts >> 8, Xs = (ts >> 3) & 31, ys0 = (ts & 7) << 2;
        u16* bufn = xt;
#pragma unroll
        for (int g = 0; g < 5; ++g) {
            SLD(0, g * 2 + 0) SLD(1, g * 2 + 1)
            SWR(0, g * 2 + 0) SWR(1, g * 2 + 1)
        }
    }
    __syncthreads();

#pragma unroll 1
    for (int k = 0; k < 4; ++k) {
        const u16* bufk = xt + (k & 1) * BUFU16;
        u16*       bufn = xt + ((k & 1) ^ 1) * BUFU16;
        const char* abase = (const char*)bufk;

        const int tk = tbase + k;
        const int b  = tk >> 8, X = (tk >> 3) & 31, y0 = (tk & 7) << 2;
        const int ts = tbase + (k < 3 ? k + 1 : 3);        // clamp: re-stage
        const int bs = ts >> 8, Xs = (ts >> 3) & 31, ys0 = (ts & 7) << 2;

        const f32x4 z4 = {0.f, 0.f, 0.f, 0.f};
        f32x4 acc00 = z4, acc01 = z4, acc10 = z4, acc11 = z4;

        // preamble: B(t1), B(t3), A(t1)
        LOADB(0, 1) LOADB(1, 3) LOAD_A4(0, 1)
        WALL()
        // taps {1,3,4,5,7,9,10,11,12,13,14,15,16,17,19,21,22,23,25}
        // region i: [SLD C=i (i<10)][SWR C=i-2][LOADB i+2][LOAD_A4 i+1][MFMA8 i] WALL
        SLD(0,0)           LOADB(2, 4)  LOAD_A4(1, 3)  MFMA8(0, 0) WALL() // t=1
        SLD(1,1)           LOADB(0, 5)  LOAD_A4(0, 4)  MFMA8(1, 1) WALL() // t=3
        SLD(2,2) SWR(0,0)  LOADB(1, 7)  LOAD_A4(1, 5)  MFMA8(2, 0) WALL() // t=4
        SLD(0,3) SWR(1,1)  LOADB(2, 9)  LOAD_A4(0, 7)  MFMA8(0, 1) WALL() // t=5
        SLD(1,4) SWR(2,2)  LOADB(0, 10) LOAD_A4(1, 9)  MFMA8(1, 0) WALL() // t=7
        SLD(2,5) SWR(0,3)  LOADB(1, 11) LOAD_A4(0, 10) MFMA8(2, 1) WALL() // t=9
        SLD(0,6) SWR(1,4)  LOADB(2, 12) LOAD_A4(1, 11) MFMA8(0, 0) WALL() // t=10
        SLD(1,7) SWR(2,5)  LOADB(0, 13) LOAD_A4(0, 12) MFMA8(1, 1) WALL() // t=11
        SLD(2,8) SWR(0,6)  LOADB(1, 14) LOAD_A4(1, 13) MFMA8(2, 0) WALL() // t=12
        SLD(0,9) SWR(1,7)  LOADB(2, 15) LOAD_A4(0, 14) MFMA8(0, 1) WALL() // t=13
                 SWR(2,8)  LOADB(0, 16) LOAD_A4(1, 15) MFMA8(1, 0) WALL() // t=14
                 SWR(0,9)  LOADB(1, 17) LOAD_A4(0, 16) MFMA8(2, 1) WALL() // t=15
                           LOADB(2, 19) LOAD_A4(1, 17) MFMA8(0, 0) WALL() // t=16
                           LOADB(0, 21) LOAD_A4(0, 19) MFMA8(1, 1) WALL() // t=17
                           LOADB(1, 22) LOAD_A4(1, 21) MFMA8(2, 0) WALL() // t=19
                           LOADB(2, 23) LOAD_A4(0, 22) MFMA8(0, 1) WALL() // t=21
                           LOADB(0, 25) LOAD_A4(1, 23) MFMA8(1, 0) WALL() // t=22
                                        LOAD_A4(0, 25) MFMA8(2, 1) WALL() // t=23
                                                       MFMA8(0, 0) WALL() // t=25

        // ---- epilogue tile k: y = y0+yh, z = mt*16+l15, ch = nh*32+nt*16+kg*4
        float* obase = out + (((size_t)(b * 32 + X) * 32 + (y0 + yh)) * 32) * 64
                     + nh * 32 + kg * 4;
        *reinterpret_cast<f32x4*>(obase + l15 * 64)             = acc00;
        *reinterpret_cast<f32x4*>(obase + l15 * 64 + 16)        = acc01;
        *reinterpret_cast<f32x4*>(obase + (16 + l15) * 64)      = acc10;
        *reinterpret_cast<f32x4*>(obase + (16 + l15) * 64 + 16) = acc11;

        __syncthreads();   // publish bufn, retire bufk reads
    }
}

extern "C" void kernel_launch(void* const* d_in, const int* in_sizes, int n_in,
                              void* d_out, int out_size, void* d_ws, size_t ws_size,
                              hipStream_t stream)
{
    const float* x    = (const float*)d_in[0];
    const float* Wsc0 = (const float*)d_in[1];
    const float* Wsc1 = (const float*)d_in[2];
    const float* w1   = (const float*)d_in[3];
    const float* w2   = (const float*)d_in[4];
    const float* w3   = (const float*)d_in[5];
    const float* w4   = (const float*)d_in[6];
    float* out = (float*)d_out;

    build_k<<<dim3(27), dim3(64), 0, stream>>>(Wsc0, Wsc1, w1, w2, w3, w4);
    conv_mfma12<<<dim3(256), dim3(512), 2 * 78848, stream>>>(x, out);
}